// Round 9
// baseline (313.380 us; speedup 1.0000x reference)
//
#include <hip/hip_runtime.h>
#include <hip/hip_bf16.h>
#include <hip/hip_fp16.h>

// GCN 2-layer forward, CSR-gather formulation.
// R9: (1) xw1 stored as fp16 -> halves the 819MB random gather in k_agg1
// (values O(1), rel err 5e-4, threshold 3.3e-3); (2) bin entries packed into
// one int (src | dloc<<17, needs N < 2^17) -> halves bin write/read traffic;
// (3) nontemporal loads on single-use streams (csr_src, bins) so L2 keeps
// xw1 rows.

#define NB2 261        // nodes per bucket (compile-time => magic-mul division)
#define CAP2 9472      // per-bucket edge capacity (mean 8352, +12 sigma)
#define MAXB 400       // static LDS sizing bound for bucket count
#define BIN_CHUNK 4096

__global__ __launch_bounds__(256) void k_bin(const int* __restrict__ src,
                                             const int* __restrict__ dst,
                                             int E, int nbuckets,
                                             int* __restrict__ binCnt,
                                             int* __restrict__ bins) {
    __shared__ int stageP[BIN_CHUNK];            // packed src|dloc (16 KB)
    __shared__ unsigned short stageB[BIN_CHUNK]; // bucket id (8 KB)
    __shared__ int lcnt[MAXB];
    __shared__ int lbase[MAXB + 1];
    __shared__ int gbase[MAXB];
    __shared__ int lpos[MAXB];
    int base = blockIdx.x * BIN_CHUNK;
    if (base >= E) return;
    int cnt_here = min(BIN_CHUNK, E - base);

    for (int b = threadIdx.x; b < nbuckets; b += 256) lcnt[b] = 0;
    __syncthreads();
    int p_[16], b_[16];
    #pragma unroll
    for (int k = 0; k < 16; k++) {
        int i = base + threadIdx.x + k * 256;
        if (i < E) {
            int s = __builtin_nontemporal_load(src + i);
            int d = __builtin_nontemporal_load(dst + i);
            int b = d / NB2;
            b_[k] = b;
            p_[k] = s | ((d - b * NB2) << 17);
            atomicAdd(&lcnt[b], 1);
        } else {
            b_[k] = -1;
        }
    }
    __syncthreads();
    if (threadIdx.x == 0) {
        int run = 0;
        for (int b = 0; b < nbuckets; b++) { lbase[b] = run; run += lcnt[b]; }
        lbase[nbuckets] = run;
    }
    __syncthreads();
    for (int b = threadIdx.x; b < nbuckets; b += 256) {
        gbase[b] = atomicAdd(&binCnt[b], lcnt[b]);
        lpos[b] = lbase[b];
    }
    __syncthreads();
    #pragma unroll
    for (int k = 0; k < 16; k++) {
        if (b_[k] >= 0) {
            int pos = atomicAdd(&lpos[b_[k]], 1);
            stageP[pos] = p_[k];
            stageB[pos] = (unsigned short)b_[k];
        }
    }
    __syncthreads();
    for (int i = threadIdx.x; i < cnt_here; i += 256) {
        int b = stageB[i];
        int gi = gbase[b] + (i - lbase[b]);
        if (gi < CAP2) bins[(size_t)b * CAP2 + gi] = stageP[i];
    }
}

// Exclusive scan of (clamped) binCnt -> bbase; rowptr[N] = total.
__global__ void k_bscan(const int* __restrict__ binCnt, int* __restrict__ bbase,
                        int nbuckets, int* __restrict__ rowptr, int N) {
    if (blockIdx.x == 0 && threadIdx.x == 0) {
        int run = 0;
        for (int b = 0; b < nbuckets; b++) {
            bbase[b] = run;
            run += min(binCnt[b], CAP2);
        }
        bbase[nbuckets] = run;
        rowptr[N] = run;
    }
}

// One block per bucket: LDS hist -> scan -> rowptr/dinv, LDS scatter -> csr.
__global__ __launch_bounds__(256) void k_csr(const int* __restrict__ bins,
                                             const int* __restrict__ binCnt,
                                             const int* __restrict__ bbase,
                                             int* __restrict__ rowptr,
                                             int* __restrict__ csr_src,
                                             float* __restrict__ dinv, int N) {
    __shared__ int hist[NB2 + 1];
    __shared__ int lrp[NB2 + 1];
    __shared__ int lcur[NB2];
    __shared__ int stage[CAP2];   // 37 KB
    int b = blockIdx.x;
    int lo = b * NB2;
    int nn = min(NB2, N - lo);
    if (nn <= 0) return;
    int m = min(binCnt[b], CAP2);
    const int* bp = bins + (size_t)b * CAP2;

    for (int t = threadIdx.x; t < nn; t += 256) hist[t] = 0;
    __syncthreads();
    for (int i = threadIdx.x; i < m; i += 256) {
        unsigned int e = (unsigned int)__builtin_nontemporal_load(bp + i);
        atomicAdd(&hist[e >> 17], 1);
    }
    __syncthreads();
    if (threadIdx.x == 0) {
        int run = 0;
        for (int t = 0; t < nn; t++) { lrp[t] = run; run += hist[t]; }
        lrp[nn] = run;
    }
    __syncthreads();
    int gb = bbase[b];
    for (int t = threadIdx.x; t < nn; t += 256) {
        rowptr[lo + t] = gb + lrp[t];
        lcur[t] = lrp[t];
        dinv[lo + t] = rsqrtf(1.0f + (float)hist[t]);
    }
    __syncthreads();
    for (int i = threadIdx.x; i < m; i += 256) {
        unsigned int e = (unsigned int)__builtin_nontemporal_load(bp + i);
        int p = atomicAdd(&lcur[e >> 17], 1);
        stage[p] = (int)(e & 0x1FFFF);
    }
    __syncthreads();
    for (int i = threadIdx.x; i < m; i += 256) {
        csr_src[gb + i] = stage[i];
    }
}

// xw1 = x[n,128] @ W1[128,64], stored fp16. Thread-per-row; acc[64] in VGPRs;
// W1 addresses lane-uniform -> scalar loads.
__global__ __launch_bounds__(256) void k_gemm1(const float* __restrict__ x,
                                               const float* __restrict__ W1,
                                               __half* __restrict__ xw, int n) {
    int row = blockIdx.x * blockDim.x + threadIdx.x;
    if (row >= n) return;
    const float* xr = x + (size_t)row * 128;

    float acc[64];
    #pragma unroll
    for (int c = 0; c < 64; ++c) acc[c] = 0.f;

    for (int k4 = 0; k4 < 32; ++k4) {
        float4 xv = *reinterpret_cast<const float4*>(xr + k4 * 4);
        const float* wp = W1 + (size_t)k4 * 4 * 64;
        #pragma unroll
        for (int c = 0; c < 64; ++c) {
            acc[c] = fmaf(xv.x, wp[c], acc[c]);
            acc[c] = fmaf(xv.y, wp[64 + c], acc[c]);
            acc[c] = fmaf(xv.z, wp[128 + c], acc[c]);
            acc[c] = fmaf(xv.w, wp[192 + c], acc[c]);
        }
    }

    __half2 hb[32];
    #pragma unroll
    for (int c = 0; c < 32; ++c) hb[c] = __floats2half2_rn(acc[2 * c], acc[2 * c + 1]);
    float4* op = reinterpret_cast<float4*>(xw + (size_t)row * 64);
    const float4* hp = reinterpret_cast<const float4*>(hb);
    #pragma unroll
    for (int i = 0; i < 8; ++i) op[i] = hp[i];
}

// Fused layer1 aggregate + tanh + GEMM2 (64->2 via wave reduction).
__global__ void k_agg1(const int* __restrict__ rowptr, const int* __restrict__ csr_src,
                       const float* __restrict__ dinv, const __half* __restrict__ xw1,
                       const float* __restrict__ b1, const float* __restrict__ W2,
                       float* __restrict__ xw2, int n) {
    int lane = threadIdx.x & 63;
    float b1v = b1[lane];
    float w2a = W2[lane * 2 + 0];
    float w2b = W2[lane * 2 + 1];
    int wid = blockIdx.x * (blockDim.x >> 6) + (threadIdx.x >> 6);
    int wtot = gridDim.x * (blockDim.x >> 6);
    for (int d = wid; d < n; d += wtot) {
        int base = rowptr[d], end = rowptr[d + 1];
        float dd = dinv[d];
        float acc = __half2float(xw1[(size_t)d * 64 + lane]) * dd * dd;
        int j = base;
        for (; j + 4 <= end; j += 4) {
            int s0 = __builtin_nontemporal_load(csr_src + j + 0);
            int s1 = __builtin_nontemporal_load(csr_src + j + 1);
            int s2 = __builtin_nontemporal_load(csr_src + j + 2);
            int s3 = __builtin_nontemporal_load(csr_src + j + 3);
            float n0 = dinv[s0] * dd, n1 = dinv[s1] * dd;
            float n2 = dinv[s2] * dd, n3 = dinv[s3] * dd;
            float v0 = __half2float(xw1[(size_t)s0 * 64 + lane]);
            float v1 = __half2float(xw1[(size_t)s1 * 64 + lane]);
            float v2 = __half2float(xw1[(size_t)s2 * 64 + lane]);
            float v3 = __half2float(xw1[(size_t)s3 * 64 + lane]);
            acc = fmaf(v0, n0, acc);
            acc = fmaf(v1, n1, acc);
            acc = fmaf(v2, n2, acc);
            acc = fmaf(v3, n3, acc);
        }
        for (; j < end; ++j) {
            int s = __builtin_nontemporal_load(csr_src + j);
            acc = fmaf(__half2float(xw1[(size_t)s * 64 + lane]), dinv[s] * dd, acc);
        }
        float h = tanhf(acc + b1v);
        float p0 = h * w2a, p1 = h * w2b;
        #pragma unroll
        for (int m = 32; m >= 1; m >>= 1) {
            p0 += __shfl_xor(p0, m);
            p1 += __shfl_xor(p1, m);
        }
        if (lane == 0) *reinterpret_cast<float2*>(xw2 + (size_t)d * 2) = make_float2(p0, p1);
    }
}

// Fused layer2 aggregate + tanh + classifier.
__global__ void k_agg2(const int* __restrict__ rowptr, const int* __restrict__ csr_src,
                       const float* __restrict__ dinv, const float* __restrict__ xw2,
                       const float* __restrict__ b2, const float* __restrict__ Wc,
                       const float* __restrict__ bc,
                       float* __restrict__ out, float* __restrict__ hout, int n) {
    int lane = threadIdx.x & 63;
    int slot = lane >> 1;
    int f = lane & 1;
    float b2v = b2[f];
    int wid = blockIdx.x * (blockDim.x >> 6) + (threadIdx.x >> 6);
    int wtot = gridDim.x * (blockDim.x >> 6);
    for (int d = wid; d < n; d += wtot) {
        int base = rowptr[d], end = rowptr[d + 1];
        float dd = dinv[d];
        float acc = (slot == 0) ? xw2[(size_t)d * 2 + f] * dd * dd : 0.f;
        for (int j = base + slot; j < end; j += 32) {
            int s = __builtin_nontemporal_load(csr_src + j);
            acc = fmaf(xw2[(size_t)s * 2 + f], dinv[s] * dd, acc);
        }
        #pragma unroll
        for (int m = 32; m >= 2; m >>= 1) acc += __shfl_xor(acc, m);
        float h = tanhf(acc + b2v);
        float other = __shfl_xor(h, 1);
        if (lane == 0) {
            *reinterpret_cast<float2*>(hout + (size_t)d * 2) = make_float2(h, other);
            float4 o;
            o.x = fmaf(h, Wc[0], fmaf(other, Wc[4], bc[0]));
            o.y = fmaf(h, Wc[1], fmaf(other, Wc[5], bc[1]));
            o.z = fmaf(h, Wc[2], fmaf(other, Wc[6], bc[2]));
            o.w = fmaf(h, Wc[3], fmaf(other, Wc[7], bc[3]));
            *reinterpret_cast<float4*>(out + (size_t)d * 4) = o;
        }
    }
}

extern "C" void kernel_launch(void* const* d_in, const int* in_sizes, int n_in,
                              void* d_out, int out_size, void* d_ws, size_t ws_size,
                              hipStream_t stream) {
    const float* x  = (const float*)d_in[0];
    const int* ei   = (const int*)d_in[1];
    const float* W1 = (const float*)d_in[2];
    const float* b1 = (const float*)d_in[3];
    const float* W2 = (const float*)d_in[4];
    const float* b2 = (const float*)d_in[5];
    const float* Wc = (const float*)d_in[6];
    const float* bc = (const float*)d_in[7];

    const int N = in_sizes[0] / 128;
    const int E = in_sizes[1] / 2;
    const int* src = ei;
    const int* dst = ei + E;

    float* out  = (float*)d_out;        // [N,4]
    float* hout = out + (size_t)N * 4;  // [N,2]

    const int NBK = (N + NB2 - 1) / NB2;   // number of buckets (384 for N=100k)

    // Workspace: csr | union(bins, xw1) | binCnt | bbase | dinv | xw2 | rowptr
    char* ws = (char*)d_ws;
    int*    csr_src = (int*)ws;                                  // E
    char*   uni     = (char*)(csr_src + E);
    int*    bins    = (int*)uni;                                 // NBK*CAP2 int (14.5 MB)
    __half* xw1     = (__half*)uni;                              // 64N halves (12.8 MB, overlays bins)
    size_t uni_sz   = (size_t)NBK * CAP2 * sizeof(int);
    size_t xw1_sz   = (size_t)N * 64 * sizeof(__half);
    char*  after    = uni + (uni_sz > xw1_sz ? uni_sz : xw1_sz);
    int*   binCnt   = (int*)after;                               // NBK
    int*   bbase    = binCnt + NBK;                              // NBK+1
    float* dinv     = (float*)(bbase + NBK + 1);                 // N
    float* xw2      = dinv + N;                                  // 2N
    int*   rowptr   = (int*)(xw2 + (size_t)N * 2);               // N+1

    (void)hipMemsetAsync(binCnt, 0, (size_t)NBK * sizeof(int), stream);
    k_bin<<<(E + BIN_CHUNK - 1) / BIN_CHUNK, 256, 0, stream>>>(src, dst, E, NBK, binCnt, bins);
    k_bscan<<<1, 64, 0, stream>>>(binCnt, bbase, NBK, rowptr, N);
    k_csr<<<NBK, 256, 0, stream>>>(bins, binCnt, bbase, rowptr, csr_src, dinv, N);

    k_gemm1<<<(N + 255) / 256, 256, 0, stream>>>(x, W1, xw1, N);
    k_agg1<<<2048, 256, 0, stream>>>(rowptr, csr_src, dinv, xw1, b1, W2, xw2, N);
    k_agg2<<<2048, 256, 0, stream>>>(rowptr, csr_src, dinv, xw2, b2, Wc, bc, out, hout, N);
}

// Round 10
// 253.118 us; speedup vs baseline: 1.2381x; 1.2381x over previous
//
#include <hip/hip_runtime.h>
#include <hip/hip_bf16.h>
#include <hip/hip_fp16.h>

// GCN 2-layer forward, CSR-gather formulation.
// R10: agg kernels are issue/latency-bound (R9: halving gather bytes left dur
// unchanged, VALUBusy 37%). So: (1) dinv is PRE-FOLDED into xw1/xw2 at
// produce time (norm = dinv[s]*dinv[d] factors: sum(xws[s])*dd) -> inner loop
// is pure gather+add; (2) k_agg1 processes TWO nodes per wave (half-wave per
// node, half2 per lane = 2 features) -> 2 rows per VMEM instr, 2x chains.

#define NB2 261        // nodes per bucket (compile-time => magic-mul division)
#define CAP2 9472      // per-bucket edge capacity (mean 8352, +12 sigma)
#define MAXB 400       // static LDS sizing bound for bucket count
#define BIN_CHUNK 4096

__global__ __launch_bounds__(256) void k_bin(const int* __restrict__ src,
                                             const int* __restrict__ dst,
                                             int E, int nbuckets,
                                             int* __restrict__ binCnt,
                                             int* __restrict__ bins) {
    __shared__ int stageP[BIN_CHUNK];            // packed src|dloc (16 KB)
    __shared__ unsigned short stageB[BIN_CHUNK]; // bucket id (8 KB)
    __shared__ int lcnt[MAXB];
    __shared__ int lbase[MAXB + 1];
    __shared__ int gbase[MAXB];
    __shared__ int lpos[MAXB];
    int base = blockIdx.x * BIN_CHUNK;
    if (base >= E) return;
    int cnt_here = min(BIN_CHUNK, E - base);

    for (int b = threadIdx.x; b < nbuckets; b += 256) lcnt[b] = 0;
    __syncthreads();
    int p_[16], b_[16];
    #pragma unroll
    for (int k = 0; k < 16; k++) {
        int i = base + threadIdx.x + k * 256;
        if (i < E) {
            int s = __builtin_nontemporal_load(src + i);
            int d = __builtin_nontemporal_load(dst + i);
            int b = d / NB2;
            b_[k] = b;
            p_[k] = s | ((d - b * NB2) << 17);
            atomicAdd(&lcnt[b], 1);
        } else {
            b_[k] = -1;
        }
    }
    __syncthreads();
    if (threadIdx.x == 0) {
        int run = 0;
        for (int b = 0; b < nbuckets; b++) { lbase[b] = run; run += lcnt[b]; }
        lbase[nbuckets] = run;
    }
    __syncthreads();
    for (int b = threadIdx.x; b < nbuckets; b += 256) {
        gbase[b] = atomicAdd(&binCnt[b], lcnt[b]);
        lpos[b] = lbase[b];
    }
    __syncthreads();
    #pragma unroll
    for (int k = 0; k < 16; k++) {
        if (b_[k] >= 0) {
            int pos = atomicAdd(&lpos[b_[k]], 1);
            stageP[pos] = p_[k];
            stageB[pos] = (unsigned short)b_[k];
        }
    }
    __syncthreads();
    for (int i = threadIdx.x; i < cnt_here; i += 256) {
        int b = stageB[i];
        int gi = gbase[b] + (i - lbase[b]);
        if (gi < CAP2) bins[(size_t)b * CAP2 + gi] = stageP[i];
    }
}

// Exclusive scan of (clamped) binCnt -> bbase; rowptr[N] = total.
__global__ void k_bscan(const int* __restrict__ binCnt, int* __restrict__ bbase,
                        int nbuckets, int* __restrict__ rowptr, int N) {
    if (blockIdx.x == 0 && threadIdx.x == 0) {
        int run = 0;
        for (int b = 0; b < nbuckets; b++) {
            bbase[b] = run;
            run += min(binCnt[b], CAP2);
        }
        bbase[nbuckets] = run;
        rowptr[N] = run;
    }
}

// One block per bucket: LDS hist -> scan -> rowptr/dinv, LDS scatter -> csr.
__global__ __launch_bounds__(256) void k_csr(const int* __restrict__ bins,
                                             const int* __restrict__ binCnt,
                                             const int* __restrict__ bbase,
                                             int* __restrict__ rowptr,
                                             int* __restrict__ csr_src,
                                             float* __restrict__ dinv, int N) {
    __shared__ int hist[NB2 + 1];
    __shared__ int lrp[NB2 + 1];
    __shared__ int lcur[NB2];
    __shared__ int stage[CAP2];   // 37 KB
    int b = blockIdx.x;
    int lo = b * NB2;
    int nn = min(NB2, N - lo);
    if (nn <= 0) return;
    int m = min(binCnt[b], CAP2);
    const int* bp = bins + (size_t)b * CAP2;

    for (int t = threadIdx.x; t < nn; t += 256) hist[t] = 0;
    __syncthreads();
    for (int i = threadIdx.x; i < m; i += 256) {
        unsigned int e = (unsigned int)__builtin_nontemporal_load(bp + i);
        atomicAdd(&hist[e >> 17], 1);
    }
    __syncthreads();
    if (threadIdx.x == 0) {
        int run = 0;
        for (int t = 0; t < nn; t++) { lrp[t] = run; run += hist[t]; }
        lrp[nn] = run;
    }
    __syncthreads();
    int gb = bbase[b];
    for (int t = threadIdx.x; t < nn; t += 256) {
        rowptr[lo + t] = gb + lrp[t];
        lcur[t] = lrp[t];
        dinv[lo + t] = rsqrtf(1.0f + (float)hist[t]);
    }
    __syncthreads();
    for (int i = threadIdx.x; i < m; i += 256) {
        unsigned int e = (unsigned int)__builtin_nontemporal_load(bp + i);
        int p = atomicAdd(&lcur[e >> 17], 1);
        stage[p] = (int)(e & 0x1FFFF);
    }
    __syncthreads();
    for (int i = threadIdx.x; i < m; i += 256) {
        csr_src[gb + i] = stage[i];
    }
}

// xw1s = (x @ W1) * dinv[row], stored fp16. Thread-per-row; acc[64] in VGPRs.
__global__ __launch_bounds__(256) void k_gemm1(const float* __restrict__ x,
                                               const float* __restrict__ W1,
                                               const float* __restrict__ dinv,
                                               __half* __restrict__ xw, int n) {
    int row = blockIdx.x * blockDim.x + threadIdx.x;
    if (row >= n) return;
    const float* xr = x + (size_t)row * 128;

    float acc[64];
    #pragma unroll
    for (int c = 0; c < 64; ++c) acc[c] = 0.f;

    for (int k4 = 0; k4 < 32; ++k4) {
        float4 xv = *reinterpret_cast<const float4*>(xr + k4 * 4);
        const float* wp = W1 + (size_t)k4 * 4 * 64;
        #pragma unroll
        for (int c = 0; c < 64; ++c) {
            acc[c] = fmaf(xv.x, wp[c], acc[c]);
            acc[c] = fmaf(xv.y, wp[64 + c], acc[c]);
            acc[c] = fmaf(xv.z, wp[128 + c], acc[c]);
            acc[c] = fmaf(xv.w, wp[192 + c], acc[c]);
        }
    }

    float di = dinv[row];
    __half2 hb[32];
    #pragma unroll
    for (int c = 0; c < 32; ++c)
        hb[c] = __floats2half2_rn(acc[2 * c] * di, acc[2 * c + 1] * di);
    float4* op = reinterpret_cast<float4*>(xw + (size_t)row * 64);
    const float4* hp = reinterpret_cast<const float4*>(hb);
    #pragma unroll
    for (int i = 0; i < 8; ++i) op[i] = hp[i];
}

// Fused layer1 aggregate + tanh + GEMM2. TWO nodes per wave (half-wave each),
// lane covers 2 features via half2. Inner loop: gather + packed add only.
// Output: xw2s[d] = (h1 @ W2) * dinv[d].
__global__ void k_agg1(const int* __restrict__ rowptr, const int* __restrict__ csr_src,
                       const float* __restrict__ dinv, const __half* __restrict__ xw1s,
                       const float* __restrict__ b1, const float* __restrict__ W2,
                       float* __restrict__ xw2s, int n) {
    int lane = threadIdx.x & 63;
    int half = lane >> 5;        // 0/1: which node of the pair
    int ln   = lane & 31;        // feature pair index (features 2ln, 2ln+1)
    float2 b1v = *reinterpret_cast<const float2*>(b1 + 2 * ln);
    float4 w2q = *reinterpret_cast<const float4*>(W2 + 4 * ln);  // rows 2ln,2ln+1 of W2[64][2]
    const __half2* xp = reinterpret_cast<const __half2*>(xw1s);

    int wid  = blockIdx.x * (blockDim.x >> 6) + (threadIdx.x >> 6);
    int wtot = gridDim.x * (blockDim.x >> 6);
    int npair = (n + 1) >> 1;
    for (int pr = wid; pr < npair; pr += wtot) {
        int d = 2 * pr + half;
        bool ok = d < n;
        int base = 0, end = 0;
        float dd = 0.f;
        if (ok) { base = rowptr[d]; end = rowptr[d + 1]; dd = dinv[d]; }
        float ax = 0.f, ay = 0.f;
        int j = base;
        for (; j + 4 <= end; j += 4) {
            int s0 = __builtin_nontemporal_load(csr_src + j + 0);
            int s1 = __builtin_nontemporal_load(csr_src + j + 1);
            int s2 = __builtin_nontemporal_load(csr_src + j + 2);
            int s3 = __builtin_nontemporal_load(csr_src + j + 3);
            float2 f0 = __half22float2(xp[(size_t)s0 * 32 + ln]);
            float2 f1 = __half22float2(xp[(size_t)s1 * 32 + ln]);
            float2 f2 = __half22float2(xp[(size_t)s2 * 32 + ln]);
            float2 f3 = __half22float2(xp[(size_t)s3 * 32 + ln]);
            ax += (f0.x + f1.x) + (f2.x + f3.x);
            ay += (f0.y + f1.y) + (f2.y + f3.y);
        }
        for (; j < end; ++j) {
            int s = __builtin_nontemporal_load(csr_src + j);
            float2 f = __half22float2(xp[(size_t)s * 32 + ln]);
            ax += f.x;
            ay += f.y;
        }
        float h0 = 0.f, h1 = 0.f;
        if (ok) {
            float2 self = __half22float2(xp[(size_t)d * 32 + ln]);
            h0 = tanhf((ax + self.x) * dd + b1v.x);
            h1 = tanhf((ay + self.y) * dd + b1v.y);
        }
        float p0 = h0 * w2q.x + h1 * w2q.z;
        float p1 = h0 * w2q.y + h1 * w2q.w;
        #pragma unroll
        for (int m = 16; m >= 1; m >>= 1) {   // reduce within 32-lane half
            p0 += __shfl_xor(p0, m);
            p1 += __shfl_xor(p1, m);
        }
        if (ok && ln == 0)
            *reinterpret_cast<float2*>(xw2s + (size_t)d * 2) = make_float2(p0 * dd, p1 * dd);
    }
}

// Fused layer2 aggregate + tanh + classifier. xw2s is pre-scaled by dinv.
__global__ void k_agg2(const int* __restrict__ rowptr, const int* __restrict__ csr_src,
                       const float* __restrict__ dinv, const float* __restrict__ xw2s,
                       const float* __restrict__ b2, const float* __restrict__ Wc,
                       const float* __restrict__ bc,
                       float* __restrict__ out, float* __restrict__ hout, int n) {
    int lane = threadIdx.x & 63;
    int slot = lane >> 1;
    int f = lane & 1;
    float b2v = b2[f];
    int wid = blockIdx.x * (blockDim.x >> 6) + (threadIdx.x >> 6);
    int wtot = gridDim.x * (blockDim.x >> 6);
    for (int d = wid; d < n; d += wtot) {
        int base = rowptr[d], end = rowptr[d + 1];
        float dd = dinv[d];
        float acc = (slot == 0) ? xw2s[(size_t)d * 2 + f] : 0.f;  // self (scaled)
        for (int j = base + slot; j < end; j += 32) {
            int s = __builtin_nontemporal_load(csr_src + j);
            acc += xw2s[(size_t)s * 2 + f];
        }
        #pragma unroll
        for (int m = 32; m >= 2; m >>= 1) acc += __shfl_xor(acc, m);
        float h = tanhf(acc * dd + b2v);
        float other = __shfl_xor(h, 1);
        if (lane == 0) {
            *reinterpret_cast<float2*>(hout + (size_t)d * 2) = make_float2(h, other);
            float4 o;
            o.x = fmaf(h, Wc[0], fmaf(other, Wc[4], bc[0]));
            o.y = fmaf(h, Wc[1], fmaf(other, Wc[5], bc[1]));
            o.z = fmaf(h, Wc[2], fmaf(other, Wc[6], bc[2]));
            o.w = fmaf(h, Wc[3], fmaf(other, Wc[7], bc[3]));
            *reinterpret_cast<float4*>(out + (size_t)d * 4) = o;
        }
    }
}

extern "C" void kernel_launch(void* const* d_in, const int* in_sizes, int n_in,
                              void* d_out, int out_size, void* d_ws, size_t ws_size,
                              hipStream_t stream) {
    const float* x  = (const float*)d_in[0];
    const int* ei   = (const int*)d_in[1];
    const float* W1 = (const float*)d_in[2];
    const float* b1 = (const float*)d_in[3];
    const float* W2 = (const float*)d_in[4];
    const float* b2 = (const float*)d_in[5];
    const float* Wc = (const float*)d_in[6];
    const float* bc = (const float*)d_in[7];

    const int N = in_sizes[0] / 128;
    const int E = in_sizes[1] / 2;
    const int* src = ei;
    const int* dst = ei + E;

    float* out  = (float*)d_out;        // [N,4]
    float* hout = out + (size_t)N * 4;  // [N,2]

    const int NBK = (N + NB2 - 1) / NB2;   // number of buckets (384 for N=100k)

    // Workspace: csr | union(bins, xw1s) | binCnt | bbase | dinv | xw2s | rowptr
    char* ws = (char*)d_ws;
    int*    csr_src = (int*)ws;                                  // E
    char*   uni     = (char*)(csr_src + E);
    int*    bins    = (int*)uni;                                 // NBK*CAP2 int (14.5 MB)
    __half* xw1s    = (__half*)uni;                              // 64N halves (12.8 MB, overlays bins)
    size_t uni_sz   = (size_t)NBK * CAP2 * sizeof(int);
    size_t xw1_sz   = (size_t)N * 64 * sizeof(__half);
    char*  after    = uni + (uni_sz > xw1_sz ? uni_sz : xw1_sz);
    int*   binCnt   = (int*)after;                               // NBK
    int*   bbase    = binCnt + NBK;                              // NBK+1
    float* dinv     = (float*)(bbase + NBK + 1);                 // N
    float* xw2s     = dinv + N;                                  // 2N
    int*   rowptr   = (int*)(xw2s + (size_t)N * 2);              // N+1

    (void)hipMemsetAsync(binCnt, 0, (size_t)NBK * sizeof(int), stream);
    k_bin<<<(E + BIN_CHUNK - 1) / BIN_CHUNK, 256, 0, stream>>>(src, dst, E, NBK, binCnt, bins);
    k_bscan<<<1, 64, 0, stream>>>(binCnt, bbase, NBK, rowptr, N);
    k_csr<<<NBK, 256, 0, stream>>>(bins, binCnt, bbase, rowptr, csr_src, dinv, N);

    k_gemm1<<<(N + 255) / 256, 256, 0, stream>>>(x, W1, dinv, xw1s, N);
    k_agg1<<<2048, 256, 0, stream>>>(rowptr, csr_src, dinv, xw1s, b1, W2, xw2s, N);
    k_agg2<<<2048, 256, 0, stream>>>(rowptr, csr_src, dinv, xw2s, b2, Wc, bc, out, hout, N);
}

// Round 11
// 231.941 us; speedup vs baseline: 1.3511x; 1.0913x over previous
//
#include <hip/hip_runtime.h>
#include <hip/hip_bf16.h>
#include <hip/hip_fp16.h>

// GCN 2-layer forward, CSR-gather formulation.
// R11: k_agg1 rewritten 4-nodes-per-wave (quarter-wave per node, 8B/lane =
// 4 features). One dwordx2 gather instr fetches 4 edges' worth of row data;
// csr indices loaded coalesced (16/quarter) and redistributed via __shfl.
// VMEM instrs/edge: ~1.0 -> ~0.33, outstanding gathers 4 -> 16. R10 showed
// the kernel is VMEM-count/latency bound (halving bytes didn't help; cutting
// instructions did).

#define NB2 261        // nodes per bucket (compile-time => magic-mul division)
#define CAP2 9472      // per-bucket edge capacity (mean 8352, +12 sigma)
#define MAXB 400       // static LDS sizing bound for bucket count
#define BIN_CHUNK 4096

__global__ __launch_bounds__(256) void k_bin(const int* __restrict__ src,
                                             const int* __restrict__ dst,
                                             int E, int nbuckets,
                                             int* __restrict__ binCnt,
                                             int* __restrict__ bins) {
    __shared__ int stageP[BIN_CHUNK];            // packed src|dloc (16 KB)
    __shared__ unsigned short stageB[BIN_CHUNK]; // bucket id (8 KB)
    __shared__ int lcnt[MAXB];
    __shared__ int lbase[MAXB + 1];
    __shared__ int gbase[MAXB];
    __shared__ int lpos[MAXB];
    int base = blockIdx.x * BIN_CHUNK;
    if (base >= E) return;
    int cnt_here = min(BIN_CHUNK, E - base);

    for (int b = threadIdx.x; b < nbuckets; b += 256) lcnt[b] = 0;
    __syncthreads();
    int p_[16], b_[16];
    #pragma unroll
    for (int k = 0; k < 16; k++) {
        int i = base + threadIdx.x + k * 256;
        if (i < E) {
            int s = __builtin_nontemporal_load(src + i);
            int d = __builtin_nontemporal_load(dst + i);
            int b = d / NB2;
            b_[k] = b;
            p_[k] = s | ((d - b * NB2) << 17);
            atomicAdd(&lcnt[b], 1);
        } else {
            b_[k] = -1;
        }
    }
    __syncthreads();
    if (threadIdx.x == 0) {
        int run = 0;
        for (int b = 0; b < nbuckets; b++) { lbase[b] = run; run += lcnt[b]; }
        lbase[nbuckets] = run;
    }
    __syncthreads();
    for (int b = threadIdx.x; b < nbuckets; b += 256) {
        gbase[b] = atomicAdd(&binCnt[b], lcnt[b]);
        lpos[b] = lbase[b];
    }
    __syncthreads();
    #pragma unroll
    for (int k = 0; k < 16; k++) {
        if (b_[k] >= 0) {
            int pos = atomicAdd(&lpos[b_[k]], 1);
            stageP[pos] = p_[k];
            stageB[pos] = (unsigned short)b_[k];
        }
    }
    __syncthreads();
    for (int i = threadIdx.x; i < cnt_here; i += 256) {
        int b = stageB[i];
        int gi = gbase[b] + (i - lbase[b]);
        if (gi < CAP2) bins[(size_t)b * CAP2 + gi] = stageP[i];
    }
}

// Exclusive scan of (clamped) binCnt -> bbase; rowptr[N] = total.
__global__ void k_bscan(const int* __restrict__ binCnt, int* __restrict__ bbase,
                        int nbuckets, int* __restrict__ rowptr, int N) {
    if (blockIdx.x == 0 && threadIdx.x == 0) {
        int run = 0;
        for (int b = 0; b < nbuckets; b++) {
            bbase[b] = run;
            run += min(binCnt[b], CAP2);
        }
        bbase[nbuckets] = run;
        rowptr[N] = run;
    }
}

// One block per bucket: LDS hist -> scan -> rowptr/dinv, LDS scatter -> csr.
__global__ __launch_bounds__(256) void k_csr(const int* __restrict__ bins,
                                             const int* __restrict__ binCnt,
                                             const int* __restrict__ bbase,
                                             int* __restrict__ rowptr,
                                             int* __restrict__ csr_src,
                                             float* __restrict__ dinv, int N) {
    __shared__ int hist[NB2 + 1];
    __shared__ int lrp[NB2 + 1];
    __shared__ int lcur[NB2];
    __shared__ int stage[CAP2];   // 37 KB
    int b = blockIdx.x;
    int lo = b * NB2;
    int nn = min(NB2, N - lo);
    if (nn <= 0) return;
    int m = min(binCnt[b], CAP2);
    const int* bp = bins + (size_t)b * CAP2;

    for (int t = threadIdx.x; t < nn; t += 256) hist[t] = 0;
    __syncthreads();
    for (int i = threadIdx.x; i < m; i += 256) {
        unsigned int e = (unsigned int)__builtin_nontemporal_load(bp + i);
        atomicAdd(&hist[e >> 17], 1);
    }
    __syncthreads();
    if (threadIdx.x == 0) {
        int run = 0;
        for (int t = 0; t < nn; t++) { lrp[t] = run; run += hist[t]; }
        lrp[nn] = run;
    }
    __syncthreads();
    int gb = bbase[b];
    for (int t = threadIdx.x; t < nn; t += 256) {
        rowptr[lo + t] = gb + lrp[t];
        lcur[t] = lrp[t];
        dinv[lo + t] = rsqrtf(1.0f + (float)hist[t]);
    }
    __syncthreads();
    for (int i = threadIdx.x; i < m; i += 256) {
        unsigned int e = (unsigned int)__builtin_nontemporal_load(bp + i);
        int p = atomicAdd(&lcur[e >> 17], 1);
        stage[p] = (int)(e & 0x1FFFF);
    }
    __syncthreads();
    for (int i = threadIdx.x; i < m; i += 256) {
        csr_src[gb + i] = stage[i];
    }
}

// xw1s = (x @ W1) * dinv[row], stored fp16. Thread-per-row; acc[64] in VGPRs.
__global__ __launch_bounds__(256) void k_gemm1(const float* __restrict__ x,
                                               const float* __restrict__ W1,
                                               const float* __restrict__ dinv,
                                               __half* __restrict__ xw, int n) {
    int row = blockIdx.x * blockDim.x + threadIdx.x;
    if (row >= n) return;
    const float* xr = x + (size_t)row * 128;

    float acc[64];
    #pragma unroll
    for (int c = 0; c < 64; ++c) acc[c] = 0.f;

    for (int k4 = 0; k4 < 32; ++k4) {
        float4 xv = *reinterpret_cast<const float4*>(xr + k4 * 4);
        const float* wp = W1 + (size_t)k4 * 4 * 64;
        #pragma unroll
        for (int c = 0; c < 64; ++c) {
            acc[c] = fmaf(xv.x, wp[c], acc[c]);
            acc[c] = fmaf(xv.y, wp[64 + c], acc[c]);
            acc[c] = fmaf(xv.z, wp[128 + c], acc[c]);
            acc[c] = fmaf(xv.w, wp[192 + c], acc[c]);
        }
    }

    float di = dinv[row];
    __half2 hb[32];
    #pragma unroll
    for (int c = 0; c < 32; ++c)
        hb[c] = __floats2half2_rn(acc[2 * c] * di, acc[2 * c + 1] * di);
    float4* op = reinterpret_cast<float4*>(xw + (size_t)row * 64);
    const float4* hp = reinterpret_cast<const float4*>(hb);
    #pragma unroll
    for (int i = 0; i < 8; ++i) op[i] = hp[i];
}

// Fused layer1 aggregate + tanh + GEMM2. FOUR nodes per wave (quarter each);
// lane = 4 features via 2x half2 (8B). csr loaded coalesced per quarter and
// redistributed via shfl; invalid slots masked into the FMA.
// Output: xw2s[d] = (h1 @ W2) * dinv[d].
__global__ void k_agg1(const int* __restrict__ rowptr, const int* __restrict__ csr_src,
                       const float* __restrict__ dinv, const __half* __restrict__ xw1s,
                       const float* __restrict__ b1, const float* __restrict__ W2,
                       float* __restrict__ xw2s, int n) {
    int lane = threadIdx.x & 63;
    int q    = lane >> 4;        // quarter 0..3 -> node
    int ln   = lane & 15;        // lane in quarter -> features 4ln..4ln+3
    float4 b1v = *reinterpret_cast<const float4*>(b1 + 4 * ln);
    float4 w2a = *reinterpret_cast<const float4*>(W2 + 8 * ln);      // rows 4ln,4ln+1
    float4 w2b = *reinterpret_cast<const float4*>(W2 + 8 * ln + 4);  // rows 4ln+2,4ln+3
    const float2* xp2 = reinterpret_cast<const float2*>(xw1s);       // 8B = 4 halves

    int wid  = blockIdx.x * (blockDim.x >> 6) + (threadIdx.x >> 6);
    int wtot = gridDim.x * (blockDim.x >> 6);
    int nquad = (n + 3) >> 2;
    for (int qd = wid; qd < nquad; qd += wtot) {
        int d = 4 * qd + q;
        bool ok = d < n;
        int base = 0, cnt = 0;
        float dd = 0.f;
        if (ok) { base = rowptr[d]; cnt = rowptr[d + 1] - base; dd = dinv[d]; }
        float a0 = 0.f, a1 = 0.f, a2 = 0.f, a3 = 0.f;

        int nch = (cnt + 15) >> 4;
        int ncm = max(nch, __shfl_xor(nch, 16));
        ncm = max(ncm, __shfl_xor(ncm, 32));   // wave-uniform max chunks

        for (int c = 0; c < ncm; ++c) {
            int rel = c * 16 + ln;
            int v = -1;
            if (rel < cnt) v = __builtin_nontemporal_load(csr_src + base + rel);
            #pragma unroll
            for (int k = 0; k < 16; ++k) {
                int sv = __shfl(v, (q << 4) | k);
                float msk = (sv >= 0) ? 1.0f : 0.0f;
                int s = min(sv & 0x1FFFF, n - 1);
                float2 r = xp2[(size_t)s * 16 + ln];
                float2 f01 = __half22float2(__builtin_bit_cast(__half2, r.x));
                float2 f23 = __half22float2(__builtin_bit_cast(__half2, r.y));
                a0 = fmaf(f01.x, msk, a0);
                a1 = fmaf(f01.y, msk, a1);
                a2 = fmaf(f23.x, msk, a2);
                a3 = fmaf(f23.y, msk, a3);
            }
        }

        float p0 = 0.f, p1 = 0.f;
        if (ok) {
            float2 r = xp2[(size_t)d * 16 + ln];   // self (pre-scaled)
            float2 s01 = __half22float2(__builtin_bit_cast(__half2, r.x));
            float2 s23 = __half22float2(__builtin_bit_cast(__half2, r.y));
            float h0 = tanhf((a0 + s01.x) * dd + b1v.x);
            float h1 = tanhf((a1 + s01.y) * dd + b1v.y);
            float h2 = tanhf((a2 + s23.x) * dd + b1v.z);
            float h3 = tanhf((a3 + s23.y) * dd + b1v.w);
            p0 = h0 * w2a.x + h1 * w2a.z + h2 * w2b.x + h3 * w2b.z;
            p1 = h0 * w2a.y + h1 * w2a.w + h2 * w2b.y + h3 * w2b.w;
        }
        #pragma unroll
        for (int m = 8; m >= 1; m >>= 1) {   // reduce within 16-lane quarter
            p0 += __shfl_xor(p0, m);
            p1 += __shfl_xor(p1, m);
        }
        if (ok && ln == 0)
            *reinterpret_cast<float2*>(xw2s + (size_t)d * 2) = make_float2(p0 * dd, p1 * dd);
    }
}

// Fused layer2 aggregate + tanh + classifier. xw2s is pre-scaled by dinv.
__global__ void k_agg2(const int* __restrict__ rowptr, const int* __restrict__ csr_src,
                       const float* __restrict__ dinv, const float* __restrict__ xw2s,
                       const float* __restrict__ b2, const float* __restrict__ Wc,
                       const float* __restrict__ bc,
                       float* __restrict__ out, float* __restrict__ hout, int n) {
    int lane = threadIdx.x & 63;
    int slot = lane >> 1;
    int f = lane & 1;
    float b2v = b2[f];
    int wid = blockIdx.x * (blockDim.x >> 6) + (threadIdx.x >> 6);
    int wtot = gridDim.x * (blockDim.x >> 6);
    for (int d = wid; d < n; d += wtot) {
        int base = rowptr[d], end = rowptr[d + 1];
        float dd = dinv[d];
        float acc = (slot == 0) ? xw2s[(size_t)d * 2 + f] : 0.f;  // self (scaled)
        for (int j = base + slot; j < end; j += 32) {
            int s = __builtin_nontemporal_load(csr_src + j);
            acc += xw2s[(size_t)s * 2 + f];
        }
        #pragma unroll
        for (int m = 32; m >= 2; m >>= 1) acc += __shfl_xor(acc, m);
        float h = tanhf(acc * dd + b2v);
        float other = __shfl_xor(h, 1);
        if (lane == 0) {
            *reinterpret_cast<float2*>(hout + (size_t)d * 2) = make_float2(h, other);
            float4 o;
            o.x = fmaf(h, Wc[0], fmaf(other, Wc[4], bc[0]));
            o.y = fmaf(h, Wc[1], fmaf(other, Wc[5], bc[1]));
            o.z = fmaf(h, Wc[2], fmaf(other, Wc[6], bc[2]));
            o.w = fmaf(h, Wc[3], fmaf(other, Wc[7], bc[3]));
            *reinterpret_cast<float4*>(out + (size_t)d * 4) = o;
        }
    }
}

extern "C" void kernel_launch(void* const* d_in, const int* in_sizes, int n_in,
                              void* d_out, int out_size, void* d_ws, size_t ws_size,
                              hipStream_t stream) {
    const float* x  = (const float*)d_in[0];
    const int* ei   = (const int*)d_in[1];
    const float* W1 = (const float*)d_in[2];
    const float* b1 = (const float*)d_in[3];
    const float* W2 = (const float*)d_in[4];
    const float* b2 = (const float*)d_in[5];
    const float* Wc = (const float*)d_in[6];
    const float* bc = (const float*)d_in[7];

    const int N = in_sizes[0] / 128;
    const int E = in_sizes[1] / 2;
    const int* src = ei;
    const int* dst = ei + E;

    float* out  = (float*)d_out;        // [N,4]
    float* hout = out + (size_t)N * 4;  // [N,2]

    const int NBK = (N + NB2 - 1) / NB2;   // number of buckets (384 for N=100k)

    // Workspace: csr | union(bins, xw1s) | binCnt | bbase | dinv | xw2s | rowptr
    char* ws = (char*)d_ws;
    int*    csr_src = (int*)ws;                                  // E
    char*   uni     = (char*)(csr_src + E);
    int*    bins    = (int*)uni;                                 // NBK*CAP2 int (14.5 MB)
    __half* xw1s    = (__half*)uni;                              // 64N halves (12.8 MB, overlays bins)
    size_t uni_sz   = (size_t)NBK * CAP2 * sizeof(int);
    size_t xw1_sz   = (size_t)N * 64 * sizeof(__half);
    char*  after    = uni + (uni_sz > xw1_sz ? uni_sz : xw1_sz);
    int*   binCnt   = (int*)after;                               // NBK
    int*   bbase    = binCnt + NBK;                              // NBK+1
    float* dinv     = (float*)(bbase + NBK + 1);                 // N
    float* xw2s     = dinv + N;                                  // 2N
    int*   rowptr   = (int*)(xw2s + (size_t)N * 2);              // N+1

    (void)hipMemsetAsync(binCnt, 0, (size_t)NBK * sizeof(int), stream);
    k_bin<<<(E + BIN_CHUNK - 1) / BIN_CHUNK, 256, 0, stream>>>(src, dst, E, NBK, binCnt, bins);
    k_bscan<<<1, 64, 0, stream>>>(binCnt, bbase, NBK, rowptr, N);
    k_csr<<<NBK, 256, 0, stream>>>(bins, binCnt, bbase, rowptr, csr_src, dinv, N);

    k_gemm1<<<(N + 255) / 256, 256, 0, stream>>>(x, W1, dinv, xw1s, N);
    k_agg1<<<2048, 256, 0, stream>>>(rowptr, csr_src, dinv, xw1s, b1, W2, xw2s, N);
    k_agg2<<<2048, 256, 0, stream>>>(rowptr, csr_src, dinv, xw2s, b2, Wc, bc, out, hout, N);
}

// Round 12
// 214.790 us; speedup vs baseline: 1.4590x; 1.0799x over previous
//
#include <hip/hip_runtime.h>
#include <hip/hip_bf16.h>
#include <hip/hip_fp16.h>

// GCN 2-layer forward, CSR-gather formulation.
// R12: k_gemm1 re-parallelized — R11 counters showed 65us with Occupancy 16%
// (391 blocks = 1.5/CU), VALUBusy 20%: latency-bound from too few waves.
// Now: 4 col-groups per row, one per wave (row = blockIdx*64 + lane,
// colgroup = tid>>6, acc[16]); grid 391 -> 1563 blocks. c0 readfirstlane'd
// so W1 loads remain scalar.

#define NB2 261        // nodes per bucket (compile-time => magic-mul division)
#define CAP2 9472      // per-bucket edge capacity (mean 8352, +12 sigma)
#define MAXB 400       // static LDS sizing bound for bucket count
#define BIN_CHUNK 4096

__global__ __launch_bounds__(256) void k_bin(const int* __restrict__ src,
                                             const int* __restrict__ dst,
                                             int E, int nbuckets,
                                             int* __restrict__ binCnt,
                                             int* __restrict__ bins) {
    __shared__ int stageP[BIN_CHUNK];            // packed src|dloc (16 KB)
    __shared__ unsigned short stageB[BIN_CHUNK]; // bucket id (8 KB)
    __shared__ int lcnt[MAXB];
    __shared__ int lbase[MAXB + 1];
    __shared__ int gbase[MAXB];
    __shared__ int lpos[MAXB];
    int base = blockIdx.x * BIN_CHUNK;
    if (base >= E) return;
    int cnt_here = min(BIN_CHUNK, E - base);

    for (int b = threadIdx.x; b < nbuckets; b += 256) lcnt[b] = 0;
    __syncthreads();
    int p_[16], b_[16];
    #pragma unroll
    for (int k = 0; k < 16; k++) {
        int i = base + threadIdx.x + k * 256;
        if (i < E) {
            int s = __builtin_nontemporal_load(src + i);
            int d = __builtin_nontemporal_load(dst + i);
            int b = d / NB2;
            b_[k] = b;
            p_[k] = s | ((d - b * NB2) << 17);
            atomicAdd(&lcnt[b], 1);
        } else {
            b_[k] = -1;
        }
    }
    __syncthreads();
    if (threadIdx.x == 0) {
        int run = 0;
        for (int b = 0; b < nbuckets; b++) { lbase[b] = run; run += lcnt[b]; }
        lbase[nbuckets] = run;
    }
    __syncthreads();
    for (int b = threadIdx.x; b < nbuckets; b += 256) {
        gbase[b] = atomicAdd(&binCnt[b], lcnt[b]);
        lpos[b] = lbase[b];
    }
    __syncthreads();
    #pragma unroll
    for (int k = 0; k < 16; k++) {
        if (b_[k] >= 0) {
            int pos = atomicAdd(&lpos[b_[k]], 1);
            stageP[pos] = p_[k];
            stageB[pos] = (unsigned short)b_[k];
        }
    }
    __syncthreads();
    for (int i = threadIdx.x; i < cnt_here; i += 256) {
        int b = stageB[i];
        int gi = gbase[b] + (i - lbase[b]);
        if (gi < CAP2) bins[(size_t)b * CAP2 + gi] = stageP[i];
    }
}

// Exclusive scan of (clamped) binCnt -> bbase; rowptr[N] = total.
__global__ void k_bscan(const int* __restrict__ binCnt, int* __restrict__ bbase,
                        int nbuckets, int* __restrict__ rowptr, int N) {
    if (blockIdx.x == 0 && threadIdx.x == 0) {
        int run = 0;
        for (int b = 0; b < nbuckets; b++) {
            bbase[b] = run;
            run += min(binCnt[b], CAP2);
        }
        bbase[nbuckets] = run;
        rowptr[N] = run;
    }
}

// One block per bucket: LDS hist -> scan -> rowptr/dinv, LDS scatter -> csr.
__global__ __launch_bounds__(256) void k_csr(const int* __restrict__ bins,
                                             const int* __restrict__ binCnt,
                                             const int* __restrict__ bbase,
                                             int* __restrict__ rowptr,
                                             int* __restrict__ csr_src,
                                             float* __restrict__ dinv, int N) {
    __shared__ int hist[NB2 + 1];
    __shared__ int lrp[NB2 + 1];
    __shared__ int lcur[NB2];
    __shared__ int stage[CAP2];   // 37 KB
    int b = blockIdx.x;
    int lo = b * NB2;
    int nn = min(NB2, N - lo);
    if (nn <= 0) return;
    int m = min(binCnt[b], CAP2);
    const int* bp = bins + (size_t)b * CAP2;

    for (int t = threadIdx.x; t < nn; t += 256) hist[t] = 0;
    __syncthreads();
    for (int i = threadIdx.x; i < m; i += 256) {
        unsigned int e = (unsigned int)__builtin_nontemporal_load(bp + i);
        atomicAdd(&hist[e >> 17], 1);
    }
    __syncthreads();
    if (threadIdx.x == 0) {
        int run = 0;
        for (int t = 0; t < nn; t++) { lrp[t] = run; run += hist[t]; }
        lrp[nn] = run;
    }
    __syncthreads();
    int gb = bbase[b];
    for (int t = threadIdx.x; t < nn; t += 256) {
        rowptr[lo + t] = gb + lrp[t];
        lcur[t] = lrp[t];
        dinv[lo + t] = rsqrtf(1.0f + (float)hist[t]);
    }
    __syncthreads();
    for (int i = threadIdx.x; i < m; i += 256) {
        unsigned int e = (unsigned int)__builtin_nontemporal_load(bp + i);
        int p = atomicAdd(&lcur[e >> 17], 1);
        stage[p] = (int)(e & 0x1FFFF);
    }
    __syncthreads();
    for (int i = threadIdx.x; i < m; i += 256) {
        csr_src[gb + i] = stage[i];
    }
}

// xw1s = (x @ W1) * dinv[row], stored fp16. 4 waves per 64-row group; wave w
// computes cols [16w,16w+16). acc[16] in VGPRs; W1 loads wave-uniform scalar.
__global__ __launch_bounds__(256) void k_gemm1(const float* __restrict__ x,
                                               const float* __restrict__ W1,
                                               const float* __restrict__ dinv,
                                               __half* __restrict__ xw, int n) {
    int lrow = threadIdx.x & 63;
    int c0 = __builtin_amdgcn_readfirstlane((threadIdx.x >> 6) * 16);
    int row = blockIdx.x * 64 + lrow;
    if (row >= n) return;
    const float* xr = x + (size_t)row * 128;

    float acc[16];
    #pragma unroll
    for (int c = 0; c < 16; ++c) acc[c] = 0.f;

    for (int k4 = 0; k4 < 32; ++k4) {
        float4 xv = *reinterpret_cast<const float4*>(xr + k4 * 4);
        const float* wp = W1 + (size_t)k4 * 4 * 64 + c0;
        #pragma unroll
        for (int c = 0; c < 16; ++c) {
            acc[c] = fmaf(xv.x, wp[c], acc[c]);
            acc[c] = fmaf(xv.y, wp[64 + c], acc[c]);
            acc[c] = fmaf(xv.z, wp[128 + c], acc[c]);
            acc[c] = fmaf(xv.w, wp[192 + c], acc[c]);
        }
    }

    float di = dinv[row];
    __half2 hb[8];
    #pragma unroll
    for (int c = 0; c < 8; ++c)
        hb[c] = __floats2half2_rn(acc[2 * c] * di, acc[2 * c + 1] * di);
    float4* op = reinterpret_cast<float4*>(xw + (size_t)row * 64 + c0);
    const float4* hp = reinterpret_cast<const float4*>(hb);
    op[0] = hp[0];
    op[1] = hp[1];
}

// Fused layer1 aggregate + tanh + GEMM2. FOUR nodes per wave (quarter each);
// lane = 4 features via 2x half2 (8B). csr loaded coalesced per quarter and
// redistributed via shfl; invalid slots masked into the FMA.
// Output: xw2s[d] = (h1 @ W2) * dinv[d].
__global__ void k_agg1(const int* __restrict__ rowptr, const int* __restrict__ csr_src,
                       const float* __restrict__ dinv, const __half* __restrict__ xw1s,
                       const float* __restrict__ b1, const float* __restrict__ W2,
                       float* __restrict__ xw2s, int n) {
    int lane = threadIdx.x & 63;
    int q    = lane >> 4;        // quarter 0..3 -> node
    int ln   = lane & 15;        // lane in quarter -> features 4ln..4ln+3
    float4 b1v = *reinterpret_cast<const float4*>(b1 + 4 * ln);
    float4 w2a = *reinterpret_cast<const float4*>(W2 + 8 * ln);      // rows 4ln,4ln+1
    float4 w2b = *reinterpret_cast<const float4*>(W2 + 8 * ln + 4);  // rows 4ln+2,4ln+3
    const float2* xp2 = reinterpret_cast<const float2*>(xw1s);       // 8B = 4 halves

    int wid  = blockIdx.x * (blockDim.x >> 6) + (threadIdx.x >> 6);
    int wtot = gridDim.x * (blockDim.x >> 6);
    int nquad = (n + 3) >> 2;
    for (int qd = wid; qd < nquad; qd += wtot) {
        int d = 4 * qd + q;
        bool ok = d < n;
        int base = 0, cnt = 0;
        float dd = 0.f;
        if (ok) { base = rowptr[d]; cnt = rowptr[d + 1] - base; dd = dinv[d]; }
        float a0 = 0.f, a1 = 0.f, a2 = 0.f, a3 = 0.f;

        int nch = (cnt + 15) >> 4;
        int ncm = max(nch, __shfl_xor(nch, 16));
        ncm = max(ncm, __shfl_xor(ncm, 32));   // wave-uniform max chunks

        for (int c = 0; c < ncm; ++c) {
            int rel = c * 16 + ln;
            int v = -1;
            if (rel < cnt) v = __builtin_nontemporal_load(csr_src + base + rel);
            #pragma unroll
            for (int k = 0; k < 16; ++k) {
                int sv = __shfl(v, (q << 4) | k);
                float msk = (sv >= 0) ? 1.0f : 0.0f;
                int s = min(sv & 0x1FFFF, n - 1);
                float2 r = xp2[(size_t)s * 16 + ln];
                float2 f01 = __half22float2(__builtin_bit_cast(__half2, r.x));
                float2 f23 = __half22float2(__builtin_bit_cast(__half2, r.y));
                a0 = fmaf(f01.x, msk, a0);
                a1 = fmaf(f01.y, msk, a1);
                a2 = fmaf(f23.x, msk, a2);
                a3 = fmaf(f23.y, msk, a3);
            }
        }

        float p0 = 0.f, p1 = 0.f;
        if (ok) {
            float2 r = xp2[(size_t)d * 16 + ln];   // self (pre-scaled)
            float2 s01 = __half22float2(__builtin_bit_cast(__half2, r.x));
            float2 s23 = __half22float2(__builtin_bit_cast(__half2, r.y));
            float h0 = tanhf((a0 + s01.x) * dd + b1v.x);
            float h1 = tanhf((a1 + s01.y) * dd + b1v.y);
            float h2 = tanhf((a2 + s23.x) * dd + b1v.z);
            float h3 = tanhf((a3 + s23.y) * dd + b1v.w);
            p0 = h0 * w2a.x + h1 * w2a.z + h2 * w2b.x + h3 * w2b.z;
            p1 = h0 * w2a.y + h1 * w2a.w + h2 * w2b.y + h3 * w2b.w;
        }
        #pragma unroll
        for (int m = 8; m >= 1; m >>= 1) {   // reduce within 16-lane quarter
            p0 += __shfl_xor(p0, m);
            p1 += __shfl_xor(p1, m);
        }
        if (ok && ln == 0)
            *reinterpret_cast<float2*>(xw2s + (size_t)d * 2) = make_float2(p0 * dd, p1 * dd);
    }
}

// Fused layer2 aggregate + tanh + classifier. xw2s is pre-scaled by dinv.
__global__ void k_agg2(const int* __restrict__ rowptr, const int* __restrict__ csr_src,
                       const float* __restrict__ dinv, const float* __restrict__ xw2s,
                       const float* __restrict__ b2, const float* __restrict__ Wc,
                       const float* __restrict__ bc,
                       float* __restrict__ out, float* __restrict__ hout, int n) {
    int lane = threadIdx.x & 63;
    int slot = lane >> 1;
    int f = lane & 1;
    float b2v = b2[f];
    int wid = blockIdx.x * (blockDim.x >> 6) + (threadIdx.x >> 6);
    int wtot = gridDim.x * (blockDim.x >> 6);
    for (int d = wid; d < n; d += wtot) {
        int base = rowptr[d], end = rowptr[d + 1];
        float dd = dinv[d];
        float acc = (slot == 0) ? xw2s[(size_t)d * 2 + f] : 0.f;  // self (scaled)
        for (int j = base + slot; j < end; j += 32) {
            int s = __builtin_nontemporal_load(csr_src + j);
            acc += xw2s[(size_t)s * 2 + f];
        }
        #pragma unroll
        for (int m = 32; m >= 2; m >>= 1) acc += __shfl_xor(acc, m);
        float h = tanhf(acc * dd + b2v);
        float other = __shfl_xor(h, 1);
        if (lane == 0) {
            *reinterpret_cast<float2*>(hout + (size_t)d * 2) = make_float2(h, other);
            float4 o;
            o.x = fmaf(h, Wc[0], fmaf(other, Wc[4], bc[0]));
            o.y = fmaf(h, Wc[1], fmaf(other, Wc[5], bc[1]));
            o.z = fmaf(h, Wc[2], fmaf(other, Wc[6], bc[2]));
            o.w = fmaf(h, Wc[3], fmaf(other, Wc[7], bc[3]));
            *reinterpret_cast<float4*>(out + (size_t)d * 4) = o;
        }
    }
}

extern "C" void kernel_launch(void* const* d_in, const int* in_sizes, int n_in,
                              void* d_out, int out_size, void* d_ws, size_t ws_size,
                              hipStream_t stream) {
    const float* x  = (const float*)d_in[0];
    const int* ei   = (const int*)d_in[1];
    const float* W1 = (const float*)d_in[2];
    const float* b1 = (const float*)d_in[3];
    const float* W2 = (const float*)d_in[4];
    const float* b2 = (const float*)d_in[5];
    const float* Wc = (const float*)d_in[6];
    const float* bc = (const float*)d_in[7];

    const int N = in_sizes[0] / 128;
    const int E = in_sizes[1] / 2;
    const int* src = ei;
    const int* dst = ei + E;

    float* out  = (float*)d_out;        // [N,4]
    float* hout = out + (size_t)N * 4;  // [N,2]

    const int NBK = (N + NB2 - 1) / NB2;   // number of buckets (384 for N=100k)

    // Workspace: csr | union(bins, xw1s) | binCnt | bbase | dinv | xw2s | rowptr
    char* ws = (char*)d_ws;
    int*    csr_src = (int*)ws;                                  // E
    char*   uni     = (char*)(csr_src + E);
    int*    bins    = (int*)uni;                                 // NBK*CAP2 int (14.5 MB)
    __half* xw1s    = (__half*)uni;                              // 64N halves (12.8 MB, overlays bins)
    size_t uni_sz   = (size_t)NBK * CAP2 * sizeof(int);
    size_t xw1_sz   = (size_t)N * 64 * sizeof(__half);
    char*  after    = uni + (uni_sz > xw1_sz ? uni_sz : xw1_sz);
    int*   binCnt   = (int*)after;                               // NBK
    int*   bbase    = binCnt + NBK;                              // NBK+1
    float* dinv     = (float*)(bbase + NBK + 1);                 // N
    float* xw2s     = dinv + N;                                  // 2N
    int*   rowptr   = (int*)(xw2s + (size_t)N * 2);              // N+1

    (void)hipMemsetAsync(binCnt, 0, (size_t)NBK * sizeof(int), stream);
    k_bin<<<(E + BIN_CHUNK - 1) / BIN_CHUNK, 256, 0, stream>>>(src, dst, E, NBK, binCnt, bins);
    k_bscan<<<1, 64, 0, stream>>>(binCnt, bbase, NBK, rowptr, N);
    k_csr<<<NBK, 256, 0, stream>>>(bins, binCnt, bbase, rowptr, csr_src, dinv, N);

    k_gemm1<<<(N + 63) / 64, 256, 0, stream>>>(x, W1, dinv, xw1s, N);
    k_agg1<<<2048, 256, 0, stream>>>(rowptr, csr_src, dinv, xw1s, b1, W2, xw2s, N);
    k_agg2<<<2048, 256, 0, stream>>>(rowptr, csr_src, dinv, xw2s, b2, Wc, bc, out, hout, N);
}